// Round 10
// baseline (279.672 us; speedup 1.0000x reference)
//
#include <hip/hip_runtime.h>

#define DIM 768
#define NHEADS 12
#define HDIM 64
#define BATCH 8
#define LQ 1024
#define LKV 1024
#define ATTN_SCALE 0.125f
#define LOG2E 1.4426950408889634f
// ATTN_SCALE * LOG2E, pre-applied to Q in proj_gemm's epilogue.
#define C1_SL2E 0.18033688011112042f

typedef __bf16 bf16;
typedef __bf16 bf16x4 __attribute__((ext_vector_type(4)));
typedef __bf16 bf16x8 __attribute__((ext_vector_type(8)));
typedef short s16x4 __attribute__((ext_vector_type(4)));
typedef float f32x4 __attribute__((ext_vector_type(4)));
typedef _Float16 f16;
typedef f16 f16x4 __attribute__((ext_vector_type(4)));

union B4 { bf16x4 h; s16x4 s; };

static __device__ __forceinline__ f32x4 mfma_k32(bf16x8 a, bf16x8 b, f32x4 c) {
    return __builtin_amdgcn_mfma_f32_16x16x32_bf16(a, b, c, 0, 0, 0);
}
static __device__ __forceinline__ f32x4 mfma_k16(s16x4 a, s16x4 b, f32x4 c) {
    return __builtin_amdgcn_mfma_f32_16x16x16bf16_1k(a, b, c, 0, 0, 0);
}

static __device__ __forceinline__ void async16(const bf16* g, bf16* l) {
    __builtin_amdgcn_global_load_lds(
        (const __attribute__((address_space(1))) unsigned int*)g,
        (__attribute__((address_space(3))) unsigned int*)l, 16, 0, 0);
}
static __device__ __forceinline__ void drain_vmem() {
    __asm__ volatile("s_waitcnt vmcnt(0)" ::: "memory");
}
// counted wait: leave the newest N vmem ops in flight
#define WAIT_VMCNT(N) __asm__ volatile("s_waitcnt vmcnt(" #N ")" ::: "memory")
// keep following LDS reads from hoisting above the barrier (rule #18-adjacent)
static __device__ __forceinline__ void code_fence() {
    __asm__ volatile("" ::: "memory");
}

// ---------------- single fused fp32 -> bf16 convert ----------------
#define NQ4 (BATCH * LQ * DIM / 4)
#define NW4 (DIM * DIM / 4)
#define NP4H (NHEADS * LQ * LKV / 4)   // pos in float4 / f16x4 units
__global__ void cvt_all(const float4* __restrict__ q, const float4* __restrict__ kv,
                        const float4* __restrict__ Wq, const float4* __restrict__ Wkv,
                        const float4* __restrict__ Wp,
                        bf16x4* __restrict__ qb, bf16x4* __restrict__ kvb,
                        bf16x4* __restrict__ wall, bf16x4* __restrict__ wpb) {
    int i = blockIdx.x * 256 + threadIdx.x;
    const float4* src; bf16x4* dst; int j;
    if (i < NQ4)                { src = q;   dst = qb;        j = i; }
    else if (i < 2 * NQ4)       { src = kv;  dst = kvb;       j = i - NQ4; }
    else if (i < 2 * NQ4 + NW4) { src = Wq;  dst = wall;      j = i - 2 * NQ4; }
    else if (i < 2 * NQ4 + 3 * NW4) { src = Wkv; dst = wall + NW4; j = i - 2 * NQ4 - NW4; }
    else if (i < 2 * NQ4 + 4 * NW4) { src = Wp;  dst = wpb;   j = i - 2 * NQ4 - 3 * NW4; }
    else return;
    float4 v = src[j];
    bf16x4 o;
    o[0] = (bf16)v.x; o[1] = (bf16)v.y; o[2] = (bf16)v.z; o[3] = (bf16)v.w;
    dst[j] = o;
}

// ---------------- fused projection GEMM: BK=64, swizzled staging + pos drive-by cvt ----
// Round-10: proj additionally converts pos fp32 -> fp16*log2e into posh (aliased
// onto d_out: written here, read by attn, overwritten by out_gemm - serial-safe).
// Per K-step each thread: 1 float4 pos load (issued after the 8 staging DMAs so
// WAIT_VMCNT(1) drains only the DMAs; the pos load lands under the MFMA phase)
// and 1 f16x4 store at iter end. Slots (bid*12+it)*256+tid cover [0,NP4H) once.
// Barriers are raw s_barrier + counted vmcnt (attn-proven) so the in-flight pos
// load is NOT force-drained (__syncthreads would insert vmcnt(0)).
__global__ __launch_bounds__(256) void proj_gemm(
    const bf16* __restrict__ qb, const bf16* __restrict__ kvb,
    const bf16* __restrict__ W,
    bf16* __restrict__ Qp, bf16* __restrict__ Kp, bf16* __restrict__ Vt,
    const float4* __restrict__ posg, f16x4* __restrict__ posh)
{
    __shared__ bf16 As[128 * 64];   // 16KB, [row][slot], slot = chunk^(row&7)
    __shared__ bf16 Bs[128 * 64];   // 16KB
    const int tid  = threadIdx.x;
    const int lane = tid & 63;
    const int w    = tid >> 6;
    const int wm = (w >> 1) * 64;
    const int wn = (w & 1) * 64;
    const int m0 = blockIdx.x * 128;
    const int n0 = blockIdx.y * 128;
    const int K = DIM;
    const int lq = lane & 15;
    const int quad = lane >> 4;

    const bf16* A = (n0 < DIM) ? qb : kvb;
    const int isV = (n0 >= 2 * DIM);

    const int rl8 = lane >> 3;                  // 0..7
    const int ch  = lane & 7;                   // 16B chunk
    const int swc = (ch ^ rl8) * 8;             // swizzled global elem offset
    const bf16* gA = A + (size_t)(m0 + w * 32 + rl8) * K + swc;
    const bf16* gB = W + (size_t)(n0 + w * 32 + rl8) * K + swc;
    bf16* lA = &As[w * 2048];                   // 32 rows * 64 elems
    bf16* lB = &Bs[w * 2048];

    const int bid = blockIdx.y * 64 + blockIdx.x;   // gridDim.x == 64
    const int slotbase = bid * 12 * 256 + tid;

    f32x4 acc[4][4] = {};

    for (int k0 = 0; k0 < K; k0 += 64) {
        const int it = k0 >> 6;                 // 0..11
        #pragma unroll
        for (int p = 0; p < 4; p++) {
            async16(gA + (size_t)(p * 8) * K + k0, lA + p * 512);
            async16(gB + (size_t)(p * 8) * K + k0, lB + p * 512);
        }
        const int slot = slotbase + it * 256;
        float4 pv = posg[slot < NP4H ? slot : (NP4H - 1)];  // unconditional: keeps vmcnt shape
        WAIT_VMCNT(1);                          // drain DMAs (+prev store); pos load stays
        __builtin_amdgcn_s_barrier();
        code_fence();

        #pragma unroll
        for (int ki = 0; ki < 2; ki++) {
            bf16x8 a[4], b[4];
            #pragma unroll
            for (int i = 0; i < 4; i++) {
                const int ra = wm + i * 16 + lq;
                a[i] = *(const bf16x8*)&As[ra * 64 + (((ki * 4 + quad) ^ (lq & 7)) * 8)];
            }
            #pragma unroll
            for (int j = 0; j < 4; j++) {
                const int rb = wn + j * 16 + lq;
                b[j] = *(const bf16x8*)&Bs[rb * 64 + (((ki * 4 + quad) ^ (lq & 7)) * 8)];
            }
            if (isV) {
                #pragma unroll
                for (int i = 0; i < 4; i++)
                    #pragma unroll
                    for (int j = 0; j < 4; j++)
                        acc[i][j] = mfma_k32(a[i], b[j], acc[i][j]);
            } else {
                #pragma unroll
                for (int i = 0; i < 4; i++)
                    #pragma unroll
                    for (int j = 0; j < 4; j++)
                        acc[i][j] = mfma_k32(b[j], a[i], acc[i][j]);
            }
        }
        __builtin_amdgcn_s_barrier();           // all waves done reading before restage
        code_fence();

        if (slot < NP4H) {                      // convert + store (drained by next vmcnt(1))
            f16x4 pf;
            pf[0] = (f16)(pv.x * LOG2E); pf[1] = (f16)(pv.y * LOG2E);
            pf[2] = (f16)(pv.z * LOG2E); pf[3] = (f16)(pv.w * LOG2E);
            posh[slot] = pf;
        }
    }

    if (isV) {
        const int n0v = n0 - 2 * DIM;
        #pragma unroll
        for (int i = 0; i < 4; i++) {
            const int base_m = m0 + wm + i * 16;
            const int b_idx = base_m >> 10;
            const int kvl = (base_m & 1023) + quad * 4;
            #pragma unroll
            for (int j = 0; j < 4; j++) {
                const int nl = n0v + wn + j * 16 + lq;
                const int h = nl >> 6;
                const int d = nl & 63;
                B4 pk;
                #pragma unroll
                for (int r = 0; r < 4; r++) pk.h[r] = (bf16)acc[i][j][r];
                *(s16x4*)&Vt[(((size_t)b_idx * NHEADS + h) * HDIM + d) * LKV + kvl] = pk.s;
            }
        }
    } else {
        bf16* Cb = (n0 < DIM) ? Qp : Kp;
        const float cs = (n0 < DIM) ? C1_SL2E : 1.0f;   // pre-scale Q only
        const int nb = (n0 < DIM) ? n0 : n0 - DIM;
        #pragma unroll
        for (int i = 0; i < 4; i++) {
            const size_t row = m0 + wm + i * 16 + lq;
            #pragma unroll
            for (int j = 0; j < 4; j++) {
                const int col = nb + wn + j * 16 + quad * 4;
                B4 pk;
                #pragma unroll
                for (int r = 0; r < 4; r++) pk.h[r] = (bf16)(acc[i][j][r] * cs);
                *(s16x4*)&Cb[row * DIM + col] = pk.s;
            }
        }
    }
}

// ---------------- final GEMM: 64x128 tiles, BK=64, swizzled staging (round-9) ----------
__global__ __launch_bounds__(256) void out_gemm(
    const bf16* __restrict__ A, const bf16* __restrict__ B,
    float* __restrict__ Cp, const float* __restrict__ bias, int M, int N, int K)
{
    __shared__ bf16 As[64 * 64];    // 8KB
    __shared__ bf16 Bs[128 * 64];   // 16KB
    const int tid  = threadIdx.x;
    const int lane = tid & 63;
    const int w    = tid >> 6;
    const int wm = (w >> 1) * 32;
    const int wn = (w & 1) * 64;
    const int m0 = blockIdx.x * 64;
    const int n0 = blockIdx.y * 128;
    const int lq = lane & 15;
    const int quad = lane >> 4;

    const int rl8 = lane >> 3;
    const int ch  = lane & 7;
    const int swc = (ch ^ rl8) * 8;
    const bf16* gA = A + (size_t)(m0 + w * 16 + rl8) * K + swc;
    const bf16* gB = B + (size_t)(n0 + w * 32 + rl8) * K + swc;
    bf16* lA = &As[w * 1024];       // 16 rows * 64
    bf16* lB = &Bs[w * 2048];       // 32 rows * 64

    f32x4 acc[2][4] = {};

    for (int k0 = 0; k0 < K; k0 += 64) {
        #pragma unroll
        for (int p = 0; p < 2; p++)
            async16(gA + (size_t)(p * 8) * K + k0, lA + p * 512);
        #pragma unroll
        for (int p = 0; p < 4; p++)
            async16(gB + (size_t)(p * 8) * K + k0, lB + p * 512);
        drain_vmem();
        __syncthreads();

        #pragma unroll
        for (int ki = 0; ki < 2; ki++) {
            bf16x8 a[2], b[4];
            #pragma unroll
            for (int i = 0; i < 2; i++) {
                const int ra = wm + i * 16 + lq;
                a[i] = *(const bf16x8*)&As[ra * 64 + (((ki * 4 + quad) ^ (lq & 7)) * 8)];
            }
            #pragma unroll
            for (int j = 0; j < 4; j++) {
                const int rb = wn + j * 16 + lq;
                b[j] = *(const bf16x8*)&Bs[rb * 64 + (((ki * 4 + quad) ^ (lq & 7)) * 8)];
            }
            #pragma unroll
            for (int i = 0; i < 2; i++)
                #pragma unroll
                for (int j = 0; j < 4; j++)
                    acc[i][j] = mfma_k32(b[j], a[i], acc[i][j]);
        }
        __syncthreads();
    }

    #pragma unroll
    for (int i = 0; i < 2; i++) {
        const size_t row = m0 + wm + i * 16 + lq;
        #pragma unroll
        for (int j = 0; j < 4; j++) {
            const int col = n0 + wn + j * 16 + quad * 4;
            float4 bj = *(const float4*)&bias[col];
            float4 o;
            o.x = acc[i][j][0] + bj.x; o.y = acc[i][j][1] + bj.y;
            o.z = acc[i][j][2] + bj.z; o.w = acc[i][j][3] + bj.w;
            *(float4*)&Cp[row * N + col] = o;
        }
    }
}

// ---------------- fused attention: QBLK=128, 8 waves, fp16 pos ----------------
// Round-10: pos is fp16 pre-scaled by log2e (written by proj_gemm into the
// d_out region). Delivery per block-iter drops 64KB -> 48KB (the round-9 model:
// ~3400 of 4250 cyc/block-iter was L2->CU delivery, half of it pos). Per-XCD
// pos working set 6MB -> 3MB: fits the 4MB L2 instead of thrashing to L3.
// Exponent is now a single add: p = exp2(sc + ph). pos loads are 4x 8B f16x4;
// vmcnt shape unchanged: [2 K/V DMAs (oldest), 4 pos loads] -> WAIT_VMCNT(4).
__global__ __launch_bounds__(512) void attn_kernel(
    const bf16* __restrict__ Qb,   // (B*LQ, 768), Q cols pre-scaled
    const bf16* __restrict__ Kb,   // (B*LKV, 768)
    const bf16* __restrict__ Vt,   // (B*H*64, LKV)
    const f16*  __restrict__ posh, // (H, LQ, LKV) fp16, pre-scaled by log2e
    bf16* __restrict__ O)          // (B*LQ, 768)
{
    __shared__ bf16 Ks[2][64 * 64];   // [buf][kv][d]  128B rows, source-swizzled
    __shared__ bf16 Vs[2][64 * 64];   // [buf][d][kv]  128B rows, source-swizzled

    const int i  = blockIdx.x;
    const int g  = (i & 7) * 12 + (i >> 6);    // (h,q0-tile) group, XCD-resident
    const int b  = (i >> 3) & 7;
    const int h  = g >> 3;
    const int q0 = (g & 7) * 128;
    const int bh = b * NHEADS + h;
    const int t = threadIdx.x;
    const int lane = t & 63;
    const int w = t >> 6;                      // 0..7 -> q-rows q0 + w*16 + lq
    const int lq = lane & 15;
    const int quad = lane >> 4;

    const bf16* qg = Qb + (size_t)(b * LQ + q0 + w * 16 + lq) * DIM + h * HDIM + quad * 8;
    bf16x8 qa0 = *(const bf16x8*)(qg);
    bf16x8 qa1 = *(const bf16x8*)(qg + 32);

    // staging: 512 threads cover 64 rows x 8 chunks; 2 DMAs per thread (K,V)
    const int srow  = t >> 3;                      // 0..63
    const int chunk = t & 7;
    const int sw    = (chunk ^ (srow & 7)) * 8;    // swizzled global-source offset
    const bf16* Kg = Kb + (size_t)(b * LKV + srow) * DIM + h * HDIM + sw;
    const bf16* Vg = Vt + (size_t)(bh * HDIM + srow) * LKV + sw;

#define STAGE(kv0, bufi) do {                                                 \
    async16(Kg + (size_t)(kv0) * DIM, &Ks[bufi][srow * 64 + chunk * 8]);      \
    async16(Vg + (kv0),               &Vs[bufi][srow * 64 + chunk * 8]);      \
} while (0)

#define NT (LKV / 64)

    const f16* pg = posh + ((size_t)h * LQ + q0 + w * 16 + lq) * LKV + quad * 4;

    // MFMA-ones operand: 4x bf16(1.0) = 0x3F80
    B4 onesb;
    onesb.s = (s16x4){0x3F80, 0x3F80, 0x3F80, 0x3F80};

    f32x4 o_acc[4] = {};
    f32x4 o_l = {};

    // prologue: tile0 DMA first (oldest), then pos(0) prefetch (4x 8B)
    STAGE(0, 0);
    f16x4 pA0 = *(const f16x4*)(pg);
    f16x4 pA1 = *(const f16x4*)(pg + 16);
    f16x4 pA2 = *(const f16x4*)(pg + 32);
    f16x4 pA3 = *(const f16x4*)(pg + 48);
    WAIT_VMCNT(4);                     // 2 DMAs done; 4 pos loads stay in flight
    __builtin_amdgcn_s_barrier();
    code_fence();

#define QK(BUF, KB, S) do {                                                                   \
    const int krow = (KB) * 16 + lq;                                                          \
    bf16x8 ak0 = *(const bf16x8*)&Ks[BUF][krow * 64 + ((quad) ^ (lq & 7)) * 8];               \
    bf16x8 ak1 = *(const bf16x8*)&Ks[BUF][krow * 64 + ((4 + quad) ^ (lq & 7)) * 8];           \
    S = mfma_k32(ak0, qa0, (f32x4){0.f, 0.f, 0.f, 0.f});                                      \
    S = mfma_k32(ak1, qa1, S);                                                                \
} while (0)

#define SMB(S, P, PF) do {                                       \
    float p0 = exp2f((S)[0] + (float)(P)[0]);                    \
    float p1 = exp2f((S)[1] + (float)(P)[1]);                    \
    float p2 = exp2f((S)[2] + (float)(P)[2]);                    \
    float p3 = exp2f((S)[3] + (float)(P)[3]);                    \
    (PF).h[0] = (bf16)p0; (PF).h[1] = (bf16)p1;                  \
    (PF).h[2] = (bf16)p2; (PF).h[3] = (bf16)p3;                  \
} while (0)

#define BODY(IT, BUF) do {                                                                     \
    if ((IT) + 1 < NT) STAGE(((IT) + 1) * 64, (BUF) ^ 1);                                      \
    const int pbn = ((IT) + 1) * 64;                                                           \
    B4 pf[4];                                                                                  \
    f32x4 s0, s1, s2, s3;                                                                      \
    __builtin_amdgcn_s_setprio(1);                                                             \
    QK(BUF, 0, s0);                                                                            \
    QK(BUF, 1, s1);                                                                            \
    SMB(s0, pA0, pf[0]); if ((IT) + 1 < NT) pA0 = *(const f16x4*)(pg + pbn);                   \
    QK(BUF, 2, s2);                                                                            \
    SMB(s1, pA1, pf[1]); if ((IT) + 1 < NT) pA1 = *(const f16x4*)(pg + pbn + 16);              \
    QK(BUF, 3, s3);                                                                            \
    SMB(s2, pA2, pf[2]); if ((IT) + 1 < NT) pA2 = *(const f16x4*)(pg + pbn + 32);              \
    SMB(s3, pA3, pf[3]); if ((IT) + 1 < NT) pA3 = *(const f16x4*)(pg + pbn + 48);              \
    _Pragma("unroll")                                                                          \
    for (int kb = 0; kb < 4; kb++)                                                             \
        o_l = mfma_k16(onesb.s, pf[kb].s, o_l);                                                \
    _Pragma("unroll")                                                                          \
    for (int db = 0; db < 4; db++) {                                                           \
        const int vrow = db * 16 + lq;                                                         \
        _Pragma("unroll")                                                                      \
        for (int kb = 0; kb < 4; kb++) {                                                       \
            s16x4 va = *(const s16x4*)&Vs[BUF][vrow * 64                                       \
                          + (((kb * 2 + (quad >> 1)) ^ (lq & 7)) * 8) + (quad & 1) * 4];       \
            o_acc[db] = mfma_k16(va, pf[kb].s, o_acc[db]);                                     \
        }                                                                                      \
    }                                                                                          \
    __builtin_amdgcn_s_setprio(0);                                                             \
    if ((IT) + 1 < NT) {                                                                       \
        WAIT_VMCNT(4);                 /* own 2 K/V DMAs done; pos stays in flight */          \
        __builtin_amdgcn_s_barrier();  /* publish tile to all waves */                         \
        code_fence();                  /* next ds_reads must not hoist above */                \
    }                                                                                          \
} while (0)

    for (int it2 = 0; it2 < NT; it2 += 2) {
        BODY(it2,     0);
        BODY(it2 + 1, 1);
    }
#undef BODY
#undef SMB
#undef QK
#undef STAGE

    // o_l holds the full row denominator (summed across all quads by the MFMA)
    float inv = 1.f / o_l[0];
    const size_t orow = (size_t)(b * LQ + q0 + w * 16 + lq) * DIM + h * HDIM;
    #pragma unroll
    for (int dblk = 0; dblk < 4; dblk++) {
        B4 ob;
        #pragma unroll
        for (int r = 0; r < 4; r++) ob.h[r] = (bf16)(o_acc[dblk][r] * inv);
        *(s16x4*)&O[orow + dblk * 16 + quad * 4] = ob.s;
    }
}

// ---------------- host ----------------
extern "C" void kernel_launch(void* const* d_in, const int* in_sizes, int n_in,
                              void* d_out, int out_size, void* d_ws, size_t ws_size,
                              hipStream_t stream) {
    const float* q     = (const float*)d_in[0];
    const float* kv    = (const float*)d_in[1];
    const float* pos   = (const float*)d_in[2];
    const float* Wq    = (const float*)d_in[3];
    const float* Wkv   = (const float*)d_in[4];
    const float* Wproj = (const float*)d_in[5];
    const float* bproj = (const float*)d_in[6];
    float* out = (float*)d_out;

    char* ws = (char*)d_ws;
    size_t off = 0;
    auto alloc = [&](size_t bytes) -> void* {
        void* p = ws + off;
        off += (bytes + 255) & ~(size_t)255;
        return p;
    };

    const int M = BATCH * LQ;
    bf16* qb   = (bf16*)alloc((size_t)M * DIM * 2);
    bf16* kvb  = (bf16*)alloc((size_t)M * DIM * 2);
    bf16* wall = (bf16*)alloc((size_t)3 * DIM * DIM * 2);
    bf16* wpb  = (bf16*)alloc((size_t)DIM * DIM * 2);
    bf16* Qp   = (bf16*)alloc((size_t)M * DIM * 2);
    bf16* Kp   = (bf16*)alloc((size_t)M * DIM * 2);
    bf16* Vt   = (bf16*)alloc((size_t)BATCH * NHEADS * HDIM * LKV * 2);
    bf16* Ob   = (bf16*)alloc((size_t)M * DIM * 2);
    // posh lives in d_out: NP4H*8B == 25,165,824 B == out_size exactly.
    // proj writes it -> attn reads it -> out_gemm overwrites d_out. Serial-safe.
    f16* posh = (f16*)out;

    {
        int total = 2 * NQ4 + 4 * NW4;
        cvt_all<<<(total + 255) / 256, 256, 0, stream>>>(
            (const float4*)q, (const float4*)kv, (const float4*)Wq,
            (const float4*)Wkv, (const float4*)Wproj,
            (bf16x4*)qb, (bf16x4*)kvb, (bf16x4*)wall, (bf16x4*)wpb);
    }

    proj_gemm<<<dim3(M / 128, (3 * DIM) / 128), 256, 0, stream>>>(
        qb, kvb, wall, Qp, Kp, Vt, (const float4*)pos, (f16x4*)posh);
    attn_kernel<<<dim3((LQ / 128) * NHEADS * BATCH), 512, 0, stream>>>(Qp, Kp, Vt, posh, Ob);
    out_gemm<<<dim3(M / 64, DIM / 128), 256, 0, stream>>>(Ob, wpb, out, bproj, M, DIM, DIM);
}